// Round 10
// baseline (223.266 us; speedup 1.0000x reference)
//
#include <hip/hip_runtime.h>
#include <cstdint>
#include <cstddef>

#define B_ 16
#define C_ 64
#define N_ 2048
#define K_ 20
#define CANDH 24
#define CAND_T 48
#define LQ 12

typedef short bf16x8 __attribute__((ext_vector_type(8)));
typedef float f32x4 __attribute__((ext_vector_type(4)));

__device__ __forceinline__ unsigned umin_(unsigned a, unsigned b) { return a < b ? a : b; }
__device__ __forceinline__ unsigned umax_(unsigned a, unsigned b) { return a > b ? a : b; }
__device__ __forceinline__ unsigned short bfr_(float v) {
    unsigned u = __float_as_uint(v);
    return (unsigned short)((u + 0x7FFFu + ((u >> 16) & 1u)) >> 16);
}

// K1: sqf = np.sum(xt*xt,-1) bit-exact (pairwise 8-acc tree);
// xh[b][n] = bf16 row with c-blocks XOR-swizzled (block cb at slot cb^(n&7));
// xrT = f32 contiguous rows for exact rescore (ws budget proven in r9).
__global__ __launch_bounds__(128) void k_sq(const float* __restrict__ x,
                                            float* __restrict__ sqf,
                                            unsigned short* __restrict__ xh,
                                            float* __restrict__ xrT) {
    int i = blockIdx.x * 128 + threadIdx.x;   // 0..B_*N_-1
    int b = i >> 11, n = i & (N_ - 1);
    const float* xb = x + (size_t)b * C_ * N_ + n;
    float vr[C_];
#pragma unroll
    for (int c = 0; c < C_; ++c) vr[c] = xb[(size_t)c * N_];
    float p[C_];
#pragma unroll
    for (int c = 0; c < C_; ++c) p[c] = __fmul_rn(vr[c], vr[c]);
    float r[8];
#pragma unroll
    for (int k = 0; k < 8; ++k) r[k] = p[k];
#pragma unroll
    for (int ii = 8; ii < 64; ii += 8) {
#pragma unroll
        for (int k = 0; k < 8; ++k) r[k] = __fadd_rn(r[k], p[ii + k]);
    }
    float s0 = __fadd_rn(__fadd_rn(r[0], r[1]), __fadd_rn(r[2], r[3]));
    float s1 = __fadd_rn(__fadd_rn(r[4], r[5]), __fadd_rn(r[6], r[7]));
    sqf[i] = __fadd_rn(s0, s1);

    unsigned short* xrow = xh + (size_t)i * 64;
#pragma unroll
    for (int cb = 0; cb < 8; ++cb) {
        bf16x8 pk;
#pragma unroll
        for (int e = 0; e < 8; ++e) pk[e] = (short)bfr_(vr[cb * 8 + e]);
        *reinterpret_cast<bf16x8*>(xrow + ((cb ^ (n & 7)) * 8)) = pk;
    }
    if (xrT) {
        float4* dst = reinterpret_cast<float4*>(xrT + (size_t)i * C_);
#pragma unroll
        for (int q = 0; q < 16; ++q)
            dst[q] = make_float4(vr[q*4+0], vr[q*4+1], vr[q*4+2], vr[q*4+3]);
    }
}

// K3: Yt[b][m][o] = sum_c (W[o][c] - W[o][64+c]) * x[b][c][m]
__global__ __launch_bounds__(256) void k_y(const float* __restrict__ x,
                                           const float* __restrict__ W,
                                           float* __restrict__ Yt) {
    __shared__ float Al[C_ * 64];
    __shared__ float xl[C_ * 64];
    int tid = threadIdx.x;
    int bid = blockIdx.x;
    int b = bid >> 5;
    int m0 = (bid & 31) * 64;
    {
        int o = tid & 63, cb = tid >> 6;
#pragma unroll
        for (int j = 0; j < 16; ++j) {
            int c = cb * 16 + j;
            Al[c * 64 + o] = W[o * 128 + c] - W[o * 128 + 64 + c];
            xl[c * 64 + o] = x[((size_t)b * C_ + c) * N_ + m0 + o];
        }
    }
    __syncthreads();
    int ml = tid & 63, og = tid >> 6;
    float acc[16];
#pragma unroll
    for (int j = 0; j < 16; ++j) acc[j] = 0.f;
#pragma unroll 4
    for (int c = 0; c < C_; ++c) {
        float xv = xl[c * 64 + ml];
        const float4* a4 = reinterpret_cast<const float4*>(&Al[c * 64 + og * 16]);
#pragma unroll
        for (int q = 0; q < 4; ++q) {
            float4 av = a4[q];
            acc[q*4+0] = fmaf(av.x, xv, acc[q*4+0]);
            acc[q*4+1] = fmaf(av.y, xv, acc[q*4+1]);
            acc[q*4+2] = fmaf(av.z, xv, acc[q*4+2]);
            acc[q*4+3] = fmaf(av.w, xv, acc[q*4+3]);
        }
    }
    float* yp = Yt + ((size_t)b * N_ + m0 + ml) * C_ + og * 16;
#pragma unroll
    for (int q = 0; q < 4; ++q)
        reinterpret_cast<float4*>(yp)[q] =
            make_float4(acc[q*4+0], acc[q*4+1], acc[q*4+2], acc[q*4+3]);
}

// K2a: MFMA distance pass, m-split x2 for occupancy. Block = 64 rows x 1024 ms
// (4 tiles of 256); 4 waves x 16 rows; A-frags in registers; per mb: 2
// ds_read_b128 + 2 mfma -> dist -> sorted-insert into per-(lane,reg) top-12.
// Each half extracts its own top-24; exact arbiter merges in k_rescore.
__global__ __launch_bounds__(256, 4) void k_dist(const unsigned short* __restrict__ xh,
                                                 const float* __restrict__ sqf,
                                                 unsigned short* __restrict__ candu) {
    __shared__ __align__(16) unsigned short xtl[256 * 64];   // 32 KB
    __shared__ float sqm[256];
    int tid = threadIdx.x;
    int w = tid >> 6, lane = tid & 63;
    int bid = blockIdx.x;             // B_*64 = 1024
    int b = bid >> 6;
    int g = bid & 63;
    int n0 = (g >> 1) * 64;
    int half = g & 1;
    int mbase = half * 1024;
    const unsigned short* xhb = xh + (size_t)b * N_ * 64;

    {   // stage 64 row-vectors (8 KB): linear coalesced copy (swizzle in xh)
#pragma unroll
        for (int i = 0; i < 2; ++i) {
            int ch = tid + 256 * i;   // chunk of 8 ushorts
            *reinterpret_cast<uint4*>(&xtl[ch * 8]) =
                *reinterpret_cast<const uint4*>(&xhb[(size_t)n0 * 64 + ch * 8]);
        }
    }
    __syncthreads();
    int rl = w * 16 + (lane & 15);    // this lane's A-row (local)
    bf16x8 afr0, afr1;
    {
        int cb0 = (lane >> 4), cb1 = 4 + (lane >> 4);
        afr0 = *reinterpret_cast<const bf16x8*>(&xtl[rl * 64 + ((cb0 ^ (rl & 7)) * 8)]);
        afr1 = *reinterpret_cast<const bf16x8*>(&xtl[rl * 64 + ((cb1 ^ (rl & 7)) * 8)]);
    }
    float rsq[4];
#pragma unroll
    for (int r = 0; r < 4; ++r)
        rsq[r] = sqf[b * N_ + n0 + w * 16 + (lane >> 4) * 4 + r];

    unsigned list[4][LQ];
#pragma unroll
    for (int r = 0; r < 4; ++r)
#pragma unroll
        for (int j = 0; j < LQ; ++j) list[r][j] = 0xFFFFFFFFu;

    for (int t = 0; t < 4; ++t) {
        int m0 = mbase + t * 256;
        __syncthreads();
        {   // stage m-tile 256x64 bf16 (32 KB): linear coalesced copy
#pragma unroll
            for (int i = 0; i < 8; ++i) {
                int ch = tid + 256 * i;
                *reinterpret_cast<uint4*>(&xtl[ch * 8]) =
                    *reinterpret_cast<const uint4*>(&xhb[(size_t)m0 * 64 + ch * 8]);
            }
            sqm[tid] = sqf[b * N_ + m0 + tid];
        }
        __syncthreads();
#pragma unroll 4
        for (int mb = 0; mb < 16; ++mb) {
            int mloc = mb * 16 + (lane & 15);
            int cb0 = (lane >> 4), cb1 = 4 + (lane >> 4);
            bf16x8 bf0 = *reinterpret_cast<const bf16x8*>(
                &xtl[mloc * 64 + ((cb0 ^ (mloc & 7)) * 8)]);
            bf16x8 bf1 = *reinterpret_cast<const bf16x8*>(
                &xtl[mloc * 64 + ((cb1 ^ (mloc & 7)) * 8)]);
            f32x4 acc = {0.f, 0.f, 0.f, 0.f};
            acc = __builtin_amdgcn_mfma_f32_16x16x32_bf16(afr0, bf0, acc, 0, 0, 0);
            acc = __builtin_amdgcn_mfma_f32_16x16x32_bf16(afr1, bf1, acc, 0, 0, 0);
            float smv = sqm[mloc];
            unsigned mg = (unsigned)(m0 + mloc);
#pragma unroll
            for (int r = 0; r < 4; ++r) {
                float d = (rsq[r] + smv) - 2.f * acc[r];
                unsigned ub = __float_as_uint(d);
                unsigned mono = (ub & 0x80000000u) ? ~ub : (ub | 0x80000000u);
                unsigned key = (mono & 0xFFFFF800u) | mg;
#pragma unroll
                for (int j = LQ - 1; j > 0; --j)
                    list[r][j] = umin_(list[r][j], umax_(list[r][j - 1], key));
                list[r][0] = umin_(list[r][0], key);
            }
        }
    }

    // extraction: 4 row-groups (16 lanes each) extract their 4 rows in
    // parallel; keys unique (low 11 bits = m, m%16 = lane&15).
#pragma unroll
    for (int j = 0; j < 4; ++j) {
        size_t grow = (size_t)b * N_ + n0 + w * 16 + (lane >> 4) * 4 + j;
#pragma unroll 1
        for (int it = 0; it < CANDH; ++it) {
            unsigned head = list[j][0];
            unsigned wv = head;
            wv = umin_(wv, (unsigned)__shfl_xor((int)wv, 1, 16));
            wv = umin_(wv, (unsigned)__shfl_xor((int)wv, 2, 16));
            wv = umin_(wv, (unsigned)__shfl_xor((int)wv, 4, 16));
            wv = umin_(wv, (unsigned)__shfl_xor((int)wv, 8, 16));
            bool own = (head == wv);
#pragma unroll
            for (int jj = 0; jj < LQ - 1; ++jj)
                list[j][jj] = own ? list[j][jj + 1] : list[j][jj];
            list[j][LQ - 1] = own ? 0xFFFFFFFFu : list[j][LQ - 1];
            if ((lane & 15) == 0)
                candu[grow * CAND_T + half * CANDH + it] = (unsigned short)(wv & 2047u);
        }
    }
}

// K2b: exact numpy-f32 rescore (sequential c, separate mul/add) + stable rank
// over 48 candidates (disjoint halves -> no duplicates). xrT contiguous rows;
// strided-x fallback kept for safety.
__global__ __launch_bounds__(256) void k_rescore(const float* __restrict__ x,
                                                 const float* __restrict__ xrT,
                                                 const float* __restrict__ sqf,
                                                 const unsigned short* __restrict__ candu,
                                                 float* __restrict__ idxf) {
    int tid = threadIdx.x;
    int w = tid >> 6, lane = tid & 63;
    size_t grow = (size_t)blockIdx.x * 4 + w;   // 0..32767
    int b = (int)(grow >> 11), n = (int)(grow & (N_ - 1));
    float d = 0.f;
    unsigned m = 0xFFFFFFFFu;
    if (xrT) {
        const float* xr = xrT + (size_t)b * N_ * C_;
        const float* xn = xr + (size_t)n * C_;
        if (lane < CAND_T) {
            m = candu[grow * CAND_T + lane];
            const float* xm = xr + (size_t)m * C_;
            float a = 0.f;
#pragma unroll 8
            for (int c = 0; c < C_; ++c)
                a = __fadd_rn(a, __fmul_rn(xn[c], xm[c]));
            d = __fadd_rn(__fsub_rn(sqf[b * N_ + n], __fmul_rn(2.0f, a)), sqf[b * N_ + m]);
        }
    } else {
        const float* xb = x + (size_t)b * C_ * N_;
        if (lane < CAND_T) {
            m = candu[grow * CAND_T + lane];
            float a = 0.f;
#pragma unroll 8
            for (int c = 0; c < C_; ++c)
                a = __fadd_rn(a, __fmul_rn(xb[(size_t)c * N_ + n], xb[(size_t)c * N_ + m]));
            d = __fadd_rn(__fsub_rn(sqf[b * N_ + n], __fmul_rn(2.0f, a)), sqf[b * N_ + m]);
        }
    }
    int rank = 0;
#pragma unroll 1
    for (int j = 0; j < CAND_T; ++j) {
        float dj = __shfl(d, j, 64);
        unsigned mj = (unsigned)__shfl((int)m, j, 64);
        if (lane < CAND_T && (dj < d || (dj == d && mj < m))) ++rank;
    }
    if (lane < CAND_T && rank < K_)
        idxf[grow * K_ + rank] = (float)m;
}

// K4: out[b][o][n] = leaky( s[o]*(u + max_k Yt[b][idx[n][k]][o]) + t[o] )
__global__ __launch_bounds__(256) void k_out(const float* __restrict__ x,
                                             const float* __restrict__ W,
                                             const float* __restrict__ gamma,
                                             const float* __restrict__ beta,
                                             const float* __restrict__ rmean,
                                             const float* __restrict__ rvar,
                                             const float* __restrict__ Yt,
                                             const float* __restrict__ idxf,
                                             float* __restrict__ out) {
    __shared__ float Bl[C_ * 64];
    __shared__ float xl[C_ * 64];
    __shared__ float resl[64 * 65];
    __shared__ float sl[64], tl[64];
    int tid = threadIdx.x;
    int bid = blockIdx.x;
    int b = bid >> 5;
    int n0 = (bid & 31) * 64;
    {
        int o = tid & 63, cb = tid >> 6;
#pragma unroll
        for (int j = 0; j < 16; ++j) {
            int c = cb * 16 + j;
            Bl[c * 64 + o] = W[o * 128 + 64 + c];
            xl[c * 64 + o] = x[((size_t)b * C_ + c) * N_ + n0 + o];
        }
        if (tid < 64) {
            float s = gamma[tid] / sqrtf(rvar[tid] + 1e-5f);
            sl[tid] = s;
            tl[tid] = beta[tid] - rmean[tid] * s;
        }
    }
    __syncthreads();
    int w = tid >> 6, o = tid & 63;
    for (int i = 0; i < 16; ++i) {
        int nl = w * 16 + i;
        int n = n0 + nl;
        float u = 0.f;
#pragma unroll 8
        for (int c = 0; c < C_; ++c)
            u = fmaf(Bl[c * 64 + o], xl[c * 64 + nl], u);
        const float* ip = idxf + ((size_t)b * N_ + n) * K_;
        float v = -3.4e38f;
#pragma unroll
        for (int k = 0; k < K_; ++k) {
            int mi = (int)ip[k];
            v = fmaxf(v, Yt[((size_t)b * N_ + mi) * C_ + o]);
        }
        float h = u + v;
        float val = sl[o] * h + tl[o];
        val = val > 0.f ? val : 0.2f * val;
        resl[o * 65 + nl] = val;
    }
    __syncthreads();
    {
        int nl = tid & 63, ob = tid >> 6;
#pragma unroll
        for (int j = 0; j < 16; ++j) {
            int o2 = ob * 16 + j;
            out[((size_t)b * C_ + o2) * N_ + n0 + nl] = resl[o2 * 65 + nl];
        }
    }
}

extern "C" void kernel_launch(void* const* d_in, const int* in_sizes, int n_in,
                              void* d_out, int out_size, void* d_ws, size_t ws_size,
                              hipStream_t stream) {
    const float* x     = (const float*)d_in[0];
    const float* W     = (const float*)d_in[1];
    const float* gamma = (const float*)d_in[2];
    const float* beta  = (const float*)d_in[3];
    const float* rmean = (const float*)d_in[4];
    const float* rvar  = (const float*)d_in[5];

    float* out  = (float*)d_out;                         // [16][64][2048]
    float* idxf = out + (size_t)B_ * C_ * N_;            // [16][2048][20] as floats

    char* ws             = (char*)d_ws;
    float* sqf           = (float*)ws;                              // 128 KB
    unsigned short* candu= (unsigned short*)(ws + 131072);          // 3.0 MB (48 x u16)
    unsigned short* xh   = (unsigned short*)(ws + 131072 + 3145728);// 4 MB
    size_t need_xrT      = (size_t)131072 + 3145728 + 4194304 + 8388608; // 15.86 MB (r9-proven)
    float* xrT           = (ws_size >= need_xrT)
                         ? (float*)(ws + 131072 + 3145728 + 4194304) : nullptr;
    // Yt (8 MB) aliases candu+xh (+head of xrT): all dead before k_y runs.
    float* Yt            = (float*)(ws + 131072);

    k_sq     <<<B_ * N_ / 128, 128, 0, stream>>>(x, sqf, xh, xrT);
    k_dist   <<<B_ * 64, 256, 0, stream>>>(xh, sqf, candu);
    k_rescore<<<B_ * N_ / 4, 256, 0, stream>>>(x, xrT, sqf, candu, idxf);
    k_y      <<<B_ * (N_ / 64), 256, 0, stream>>>(x, W, Yt);
    k_out    <<<B_ * (N_ / 64), 256, 0, stream>>>(x, W, gamma, beta, rmean, rvar, Yt, idxf, out);
}

// Round 11
// 198.647 us; speedup vs baseline: 1.1239x; 1.1239x over previous
//
#include <hip/hip_runtime.h>
#include <cstdint>
#include <cstddef>

#define B_ 16
#define C_ 64
#define N_ 2048
#define K_ 20
#define CAND 24
#define LQ 12

typedef short bf16x8 __attribute__((ext_vector_type(8)));
typedef float f32x4 __attribute__((ext_vector_type(4)));

__device__ __forceinline__ unsigned umin_(unsigned a, unsigned b) { return a < b ? a : b; }
__device__ __forceinline__ unsigned umax_(unsigned a, unsigned b) { return a > b ? a : b; }
__device__ __forceinline__ unsigned short bfr_(float v) {
    unsigned u = __float_as_uint(v);
    return (unsigned short)((u + 0x7FFFu + ((u >> 16) & 1u)) >> 16);
}

// K1: sqf = np.sum(xt*xt,-1) bit-exact (pairwise 8-acc tree);
// xh = bf16 rows, c-blocks XOR-swizzled (block cb at slot cb^(n&7));
// xrT = f32 contiguous rows for the exact rescore;
// optional fused Y: Yt[n][o] = sum_c (Wl-Wr)[o][c] * x[c][n]  (ws-gated).
__global__ __launch_bounds__(128) void k_sq(const float* __restrict__ x,
                                            float* __restrict__ sqf,
                                            unsigned short* __restrict__ xh,
                                            float* __restrict__ xrT,
                                            float* __restrict__ Yt,
                                            const float* __restrict__ W) {
    __shared__ float Ag[C_ * 64];   // [c][o]
    int tid = threadIdx.x;
    bool doY = (Yt != nullptr);
    if (doY) {
        int o = tid & 63, ch = tid >> 6;
#pragma unroll
        for (int j = 0; j < 32; ++j) {
            int c = ch * 32 + j;
            Ag[c * 64 + o] = W[o * 128 + c] - W[o * 128 + 64 + c];
        }
    }
    int i = blockIdx.x * 128 + tid;   // 0..B_*N_-1
    int b = i >> 11, n = i & (N_ - 1);
    const float* xb = x + (size_t)b * C_ * N_ + n;
    float vr[C_];
#pragma unroll
    for (int c = 0; c < C_; ++c) vr[c] = xb[(size_t)c * N_];
    float p[C_];
#pragma unroll
    for (int c = 0; c < C_; ++c) p[c] = __fmul_rn(vr[c], vr[c]);
    float r[8];
#pragma unroll
    for (int k = 0; k < 8; ++k) r[k] = p[k];
#pragma unroll
    for (int ii = 8; ii < 64; ii += 8) {
#pragma unroll
        for (int k = 0; k < 8; ++k) r[k] = __fadd_rn(r[k], p[ii + k]);
    }
    float s0 = __fadd_rn(__fadd_rn(r[0], r[1]), __fadd_rn(r[2], r[3]));
    float s1 = __fadd_rn(__fadd_rn(r[4], r[5]), __fadd_rn(r[6], r[7]));
    sqf[i] = __fadd_rn(s0, s1);

    unsigned short* xrow = xh + (size_t)i * 64;
#pragma unroll
    for (int cb = 0; cb < 8; ++cb) {
        bf16x8 pk;
#pragma unroll
        for (int e = 0; e < 8; ++e) pk[e] = (short)bfr_(vr[cb * 8 + e]);
        *reinterpret_cast<bf16x8*>(xrow + ((cb ^ (n & 7)) * 8)) = pk;
    }
    if (xrT) {
        float4* dst = reinterpret_cast<float4*>(xrT + (size_t)i * C_);
#pragma unroll
        for (int q = 0; q < 16; ++q)
            dst[q] = make_float4(vr[q*4+0], vr[q*4+1], vr[q*4+2], vr[q*4+3]);
    }
    if (doY) {
        __syncthreads();
        float4 acc[16];
#pragma unroll
        for (int q = 0; q < 16; ++q) acc[q] = make_float4(0.f, 0.f, 0.f, 0.f);
#pragma unroll 4
        for (int c = 0; c < C_; ++c) {
            float xv = vr[c];
            const float4* a4 = reinterpret_cast<const float4*>(&Ag[c * 64]);
#pragma unroll
            for (int q = 0; q < 16; ++q) {
                float4 a = a4[q];
                acc[q].x = fmaf(xv, a.x, acc[q].x);
                acc[q].y = fmaf(xv, a.y, acc[q].y);
                acc[q].z = fmaf(xv, a.z, acc[q].z);
                acc[q].w = fmaf(xv, a.w, acc[q].w);
            }
        }
        float4* yp = reinterpret_cast<float4*>(Yt + (size_t)i * 64);
#pragma unroll
        for (int q = 0; q < 16; ++q) yp[q] = acc[q];
    }
}

// K3 (fallback when ws can't hold a dedicated Yt): Yt[m][o] = (Wl-Wr)x
__global__ __launch_bounds__(256) void k_y(const float* __restrict__ x,
                                           const float* __restrict__ W,
                                           float* __restrict__ Yt) {
    __shared__ float Al[C_ * 64];
    __shared__ float xl[C_ * 64];
    int tid = threadIdx.x;
    int bid = blockIdx.x;
    int b = bid >> 5;
    int m0 = (bid & 31) * 64;
    {
        int o = tid & 63, cb = tid >> 6;
#pragma unroll
        for (int j = 0; j < 16; ++j) {
            int c = cb * 16 + j;
            Al[c * 64 + o] = W[o * 128 + c] - W[o * 128 + 64 + c];
            xl[c * 64 + o] = x[((size_t)b * C_ + c) * N_ + m0 + o];
        }
    }
    __syncthreads();
    int ml = tid & 63, og = tid >> 6;
    float acc[16];
#pragma unroll
    for (int j = 0; j < 16; ++j) acc[j] = 0.f;
#pragma unroll 4
    for (int c = 0; c < C_; ++c) {
        float xv = xl[c * 64 + ml];
        const float4* a4 = reinterpret_cast<const float4*>(&Al[c * 64 + og * 16]);
#pragma unroll
        for (int q = 0; q < 4; ++q) {
            float4 av = a4[q];
            acc[q*4+0] = fmaf(av.x, xv, acc[q*4+0]);
            acc[q*4+1] = fmaf(av.y, xv, acc[q*4+1]);
            acc[q*4+2] = fmaf(av.z, xv, acc[q*4+2]);
            acc[q*4+3] = fmaf(av.w, xv, acc[q*4+3]);
        }
    }
    float* yp = Yt + ((size_t)b * N_ + m0 + ml) * C_ + og * 16;
#pragma unroll
    for (int q = 0; q < 4; ++q)
        reinterpret_cast<float4*>(yp)[q] =
            make_float4(acc[q*4+0], acc[q*4+1], acc[q*4+2], acc[q*4+3]);
}

// K2a: MFMA distance pass (r9 structure + slim keys + imm-offset ds reads +
// ILP'd extraction). 4 waves x 16 rows; 8 m-tiles of 256.
__global__ __launch_bounds__(256) void k_dist(const unsigned short* __restrict__ xh,
                                              const float* __restrict__ sqf,
                                              unsigned short* __restrict__ candu) {
    __shared__ __align__(16) unsigned short xtl[256 * 64];   // 32 KB
    __shared__ float sqm[256];
    int tid = threadIdx.x;
    int w = tid >> 6, lane = tid & 63;
    int bid = blockIdx.x;             // B_*32 = 512
    int b = bid >> 5;
    int n0 = (bid & 31) * 64;
    const unsigned short* xhb = xh + (size_t)b * N_ * 64;

    {   // stage 64 row-vectors (8 KB): linear coalesced copy (swizzle in xh)
#pragma unroll
        for (int i = 0; i < 2; ++i) {
            int ch = tid + 256 * i;
            *reinterpret_cast<uint4*>(&xtl[ch * 8]) =
                *reinterpret_cast<const uint4*>(&xhb[(size_t)n0 * 64 + ch * 8]);
        }
    }
    __syncthreads();
    int rl = w * 16 + (lane & 15);
    int cb0 = (lane >> 4), cb1 = 4 + (lane >> 4);
    bf16x8 afr0 = *reinterpret_cast<const bf16x8*>(&xtl[rl * 64 + ((cb0 ^ (lane & 7)) * 8)]);
    bf16x8 afr1 = *reinterpret_cast<const bf16x8*>(&xtl[rl * 64 + ((cb1 ^ (lane & 7)) * 8)]);
    float rsq[4];
#pragma unroll
    for (int r = 0; r < 4; ++r)
        rsq[r] = sqf[b * N_ + n0 + w * 16 + (lane >> 4) * 4 + r];

    unsigned list[4][LQ];
#pragma unroll
    for (int r = 0; r < 4; ++r)
#pragma unroll
        for (int j = 0; j < LQ; ++j) list[r][j] = 0xFFFFFFFFu;

    for (int t = 0; t < 8; ++t) {
        int m0 = t * 256;
        __syncthreads();
        {   // stage m-tile 256x64 bf16 (32 KB): linear coalesced copy
#pragma unroll
            for (int i = 0; i < 8; ++i) {
                int ch = tid + 256 * i;
                *reinterpret_cast<uint4*>(&xtl[ch * 8]) =
                    *reinterpret_cast<const uint4*>(&xhb[(size_t)m0 * 64 + ch * 8]);
            }
            sqm[tid] = sqf[b * N_ + m0 + tid];
        }
        __syncthreads();
        // per-lane bases: (mb*16)&7==0 -> swizzle slot is mb-invariant;
        // full unroll gives ds_read_b128 with immediate offsets (zero addr VALU)
        const unsigned short* pB0 = &xtl[(lane & 15) * 64 + ((cb0 ^ (lane & 7)) * 8)];
        const unsigned short* pB1 = &xtl[(lane & 15) * 64 + ((cb1 ^ (lane & 7)) * 8)];
        const float* pS = &sqm[lane & 15];
#pragma unroll
        for (int mb = 0; mb < 16; ++mb) {
            bf16x8 bf0 = *reinterpret_cast<const bf16x8*>(pB0 + mb * 1024);
            bf16x8 bf1 = *reinterpret_cast<const bf16x8*>(pB1 + mb * 1024);
            f32x4 acc = {0.f, 0.f, 0.f, 0.f};
            acc = __builtin_amdgcn_mfma_f32_16x16x32_bf16(afr0, bf0, acc, 0, 0, 0);
            acc = __builtin_amdgcn_mfma_f32_16x16x32_bf16(afr1, bf1, acc, 0, 0, 0);
            float smv = pS[mb * 16];
            unsigned mg = (unsigned)(m0 + mb * 16) | (unsigned)(lane & 15);
#pragma unroll
            for (int r = 0; r < 4; ++r) {
                float rs = rsq[r] + smv;
                float d = fmaf(-2.f, acc[r], rs);
                d = fmaxf(d, 0.f);   // d>=0: IEEE bits are unsigned-monotone
                unsigned key = (__float_as_uint(d) & 0xFFFFF800u) | mg;
#pragma unroll
                for (int j = LQ - 1; j > 0; --j)
                    list[r][j] = umin_(list[r][j], umax_(list[r][j - 1], key));
                list[r][0] = umin_(list[r][0], key);
            }
        }
    }

    // extraction: 24 rounds; all 4 row-groups' shfl chains interleaved (ILP).
    // keys unique (low 11 bits = m, m%16 = lane&15) -> exactly one owner pops.
    size_t grow0 = (size_t)b * N_ + n0 + w * 16 + (lane >> 4) * 4;
#pragma unroll 1
    for (int it = 0; it < CAND; ++it) {
        unsigned head[4], wv[4];
#pragma unroll
        for (int j = 0; j < 4; ++j) { head[j] = list[j][0]; wv[j] = head[j]; }
#pragma unroll
        for (int d2 = 1; d2 < 16; d2 <<= 1)
#pragma unroll
            for (int j = 0; j < 4; ++j)
                wv[j] = umin_(wv[j], (unsigned)__shfl_xor((int)wv[j], d2, 16));
#pragma unroll
        for (int j = 0; j < 4; ++j) {
            bool own = (head[j] == wv[j]);
#pragma unroll
            for (int jj = 0; jj < LQ - 1; ++jj)
                list[j][jj] = own ? list[j][jj + 1] : list[j][jj];
            list[j][LQ - 1] = own ? 0xFFFFFFFFu : list[j][LQ - 1];
            if ((lane & 15) == 0)
                candu[(grow0 + j) * CAND + it] = (unsigned short)(wv[j] & 2047u);
        }
    }
}

// K2b: exact numpy-f32 rescore (sequential c, separate mul/add) + stable rank.
__global__ __launch_bounds__(256) void k_rescore(const float* __restrict__ x,
                                                 const float* __restrict__ xrT,
                                                 const float* __restrict__ sqf,
                                                 const unsigned short* __restrict__ candu,
                                                 float* __restrict__ idxf) {
    int tid = threadIdx.x;
    int w = tid >> 6, lane = tid & 63;
    size_t grow = (size_t)blockIdx.x * 4 + w;   // 0..32767
    int b = (int)(grow >> 11), n = (int)(grow & (N_ - 1));
    float d = 0.f;
    unsigned m = 0xFFFFFFFFu;
    if (xrT) {
        const float* xr = xrT + (size_t)b * N_ * C_;
        const float* xn = xr + (size_t)n * C_;
        if (lane < CAND) {
            m = candu[grow * CAND + lane];
            const float* xm = xr + (size_t)m * C_;
            float a = 0.f;
#pragma unroll 8
            for (int c = 0; c < C_; ++c)
                a = __fadd_rn(a, __fmul_rn(xn[c], xm[c]));
            d = __fadd_rn(__fsub_rn(sqf[b * N_ + n], __fmul_rn(2.0f, a)), sqf[b * N_ + m]);
        }
    } else {
        const float* xb = x + (size_t)b * C_ * N_;
        if (lane < CAND) {
            m = candu[grow * CAND + lane];
            float a = 0.f;
#pragma unroll 8
            for (int c = 0; c < C_; ++c)
                a = __fadd_rn(a, __fmul_rn(xb[(size_t)c * N_ + n], xb[(size_t)c * N_ + m]));
            d = __fadd_rn(__fsub_rn(sqf[b * N_ + n], __fmul_rn(2.0f, a)), sqf[b * N_ + m]);
        }
    }
    int rank = 0;
#pragma unroll 1
    for (int j = 0; j < CAND; ++j) {
        float dj = __shfl(d, j, 64);
        unsigned mj = (unsigned)__shfl((int)m, j, 64);
        if (lane < CAND && (dj < d || (dj == d && mj < m))) ++rank;
    }
    if (lane < CAND && rank < K_)
        idxf[grow * K_ + rank] = (float)m;
}

// K4: out[b][o][n] = leaky( s[o]*(u + max_k Yt[b][idx[n][k]][o]) + t[o] )
__global__ __launch_bounds__(256) void k_out(const float* __restrict__ x,
                                             const float* __restrict__ W,
                                             const float* __restrict__ gamma,
                                             const float* __restrict__ beta,
                                             const float* __restrict__ rmean,
                                             const float* __restrict__ rvar,
                                             const float* __restrict__ Yt,
                                             const float* __restrict__ idxf,
                                             float* __restrict__ out) {
    __shared__ float Bl[C_ * 64];
    __shared__ float xl[C_ * 64];
    __shared__ float resl[64 * 65];
    __shared__ float sl[64], tl[64];
    int tid = threadIdx.x;
    int bid = blockIdx.x;
    int b = bid >> 5;
    int n0 = (bid & 31) * 64;
    {
        int o = tid & 63, cb = tid >> 6;
#pragma unroll
        for (int j = 0; j < 16; ++j) {
            int c = cb * 16 + j;
            Bl[c * 64 + o] = W[o * 128 + 64 + c];
            xl[c * 64 + o] = x[((size_t)b * C_ + c) * N_ + n0 + o];
        }
        if (tid < 64) {
            float s = gamma[tid] / sqrtf(rvar[tid] + 1e-5f);
            sl[tid] = s;
            tl[tid] = beta[tid] - rmean[tid] * s;
        }
    }
    __syncthreads();
    int w = tid >> 6, o = tid & 63;
    for (int i = 0; i < 16; ++i) {
        int nl = w * 16 + i;
        int n = n0 + nl;
        float u = 0.f;
#pragma unroll 8
        for (int c = 0; c < C_; ++c)
            u = fmaf(Bl[c * 64 + o], xl[c * 64 + nl], u);
        const float* ip = idxf + ((size_t)b * N_ + n) * K_;
        float v = -3.4e38f;
#pragma unroll
        for (int k = 0; k < K_; ++k) {
            int mi = (int)ip[k];
            v = fmaxf(v, Yt[((size_t)b * N_ + mi) * C_ + o]);
        }
        float h = u + v;
        float val = sl[o] * h + tl[o];
        val = val > 0.f ? val : 0.2f * val;
        resl[o * 65 + nl] = val;
    }
    __syncthreads();
    {
        int nl = tid & 63, ob = tid >> 6;
#pragma unroll
        for (int j = 0; j < 16; ++j) {
            int o2 = ob * 16 + j;
            out[((size_t)b * C_ + o2) * N_ + n0 + nl] = resl[o2 * 65 + nl];
        }
    }
}

extern "C" void kernel_launch(void* const* d_in, const int* in_sizes, int n_in,
                              void* d_out, int out_size, void* d_ws, size_t ws_size,
                              hipStream_t stream) {
    const float* x     = (const float*)d_in[0];
    const float* W     = (const float*)d_in[1];
    const float* gamma = (const float*)d_in[2];
    const float* beta  = (const float*)d_in[3];
    const float* rmean = (const float*)d_in[4];
    const float* rvar  = (const float*)d_in[5];

    float* out  = (float*)d_out;                         // [16][64][2048]
    float* idxf = out + (size_t)B_ * C_ * N_;            // [16][2048][20] as floats

    char* ws = (char*)d_ws;
    // layout: sqf 128K | candu u16x24 1.5M | xh 4M | xrT 8M | [Yt 8M if room]
    float* sqf            = (float*)ws;
    unsigned short* candu = (unsigned short*)(ws + 131072);
    unsigned short* xh    = (unsigned short*)(ws + 131072 + 1572864);
    size_t off_xrT        = 131072 + 1572864 + 4194304;              // 5.90 MB
    size_t need_xrT       = off_xrT + 8388608;                       // 14.28 MB (< r9-proven 15.86)
    size_t need_fused     = need_xrT + 8388608;                      // 22.68 MB
    float* xrT            = (ws_size >= need_xrT) ? (float*)(ws + off_xrT) : nullptr;
    bool fused            = (ws_size >= need_fused);
    // fallback Yt aliases candu+xh+xrT-head (all dead before k_y runs)
    float* Yt             = fused ? (float*)(ws + need_xrT) : (float*)(ws + 131072);

    k_sq     <<<B_ * N_ / 128, 128, 0, stream>>>(x, sqf, xh, xrT, fused ? Yt : nullptr, W);
    k_dist   <<<B_ * 32, 256, 0, stream>>>(xh, sqf, candu);
    k_rescore<<<B_ * N_ / 4, 256, 0, stream>>>(x, xrT, sqf, candu, idxf);
    if (!fused)
        k_y  <<<B_ * (N_ / 64), 256, 0, stream>>>(x, W, Yt);
    k_out    <<<B_ * (N_ / 64), 256, 0, stream>>>(x, W, gamma, beta, rmean, rvar, Yt, idxf, out);
}

// Round 12
// 198.209 us; speedup vs baseline: 1.1264x; 1.0022x over previous
//
#include <hip/hip_runtime.h>
#include <cstdint>
#include <cstddef>

#define B_ 16
#define C_ 64
#define N_ 2048
#define K_ 20
#define CAND 24
#define LQ 12

typedef short bf16x8 __attribute__((ext_vector_type(8)));
typedef float f32x4 __attribute__((ext_vector_type(4)));

__device__ __forceinline__ unsigned umin_(unsigned a, unsigned b) { return a < b ? a : b; }
__device__ __forceinline__ unsigned umax_(unsigned a, unsigned b) { return a > b ? a : b; }
__device__ __forceinline__ unsigned short bfr_(float v) {
    unsigned u = __float_as_uint(v);
    return (unsigned short)((u + 0x7FFFu + ((u >> 16) & 1u)) >> 16);
}

// K1: sqf = np.sum(xt*xt,-1) bit-exact (pairwise 8-acc tree);
// xh = bf16 rows, c-blocks XOR-swizzled (block cb at slot cb^(n&7));
// xrT = f32 contiguous rows for the exact rescore;
// optional fused Y: Yt[n][o] = sum_c (Wl-Wr)[o][c] * x[c][n]  (ws-gated).
__global__ __launch_bounds__(128) void k_sq(const float* __restrict__ x,
                                            float* __restrict__ sqf,
                                            unsigned short* __restrict__ xh,
                                            float* __restrict__ xrT,
                                            float* __restrict__ Yt,
                                            const float* __restrict__ W) {
    __shared__ float Ag[C_ * 64];   // [c][o]
    int tid = threadIdx.x;
    bool doY = (Yt != nullptr);
    if (doY) {
        int o = tid & 63, ch = tid >> 6;
#pragma unroll
        for (int j = 0; j < 32; ++j) {
            int c = ch * 32 + j;
            Ag[c * 64 + o] = W[o * 128 + c] - W[o * 128 + 64 + c];
        }
    }
    int i = blockIdx.x * 128 + tid;   // 0..B_*N_-1
    int b = i >> 11, n = i & (N_ - 1);
    const float* xb = x + (size_t)b * C_ * N_ + n;
    float vr[C_];
#pragma unroll
    for (int c = 0; c < C_; ++c) vr[c] = xb[(size_t)c * N_];
    float p[C_];
#pragma unroll
    for (int c = 0; c < C_; ++c) p[c] = __fmul_rn(vr[c], vr[c]);
    float r[8];
#pragma unroll
    for (int k = 0; k < 8; ++k) r[k] = p[k];
#pragma unroll
    for (int ii = 8; ii < 64; ii += 8) {
#pragma unroll
        for (int k = 0; k < 8; ++k) r[k] = __fadd_rn(r[k], p[ii + k]);
    }
    float s0 = __fadd_rn(__fadd_rn(r[0], r[1]), __fadd_rn(r[2], r[3]));
    float s1 = __fadd_rn(__fadd_rn(r[4], r[5]), __fadd_rn(r[6], r[7]));
    sqf[i] = __fadd_rn(s0, s1);

    unsigned short* xrow = xh + (size_t)i * 64;
#pragma unroll
    for (int cb = 0; cb < 8; ++cb) {
        bf16x8 pk;
#pragma unroll
        for (int e = 0; e < 8; ++e) pk[e] = (short)bfr_(vr[cb * 8 + e]);
        *reinterpret_cast<bf16x8*>(xrow + ((cb ^ (n & 7)) * 8)) = pk;
    }
    if (xrT) {
        float4* dst = reinterpret_cast<float4*>(xrT + (size_t)i * C_);
#pragma unroll
        for (int q = 0; q < 16; ++q)
            dst[q] = make_float4(vr[q*4+0], vr[q*4+1], vr[q*4+2], vr[q*4+3]);
    }
    if (doY) {
        __syncthreads();
        float4 acc[16];
#pragma unroll
        for (int q = 0; q < 16; ++q) acc[q] = make_float4(0.f, 0.f, 0.f, 0.f);
#pragma unroll 4
        for (int c = 0; c < C_; ++c) {
            float xv = vr[c];
            const float4* a4 = reinterpret_cast<const float4*>(&Ag[c * 64]);
#pragma unroll
            for (int q = 0; q < 16; ++q) {
                float4 a = a4[q];
                acc[q].x = fmaf(xv, a.x, acc[q].x);
                acc[q].y = fmaf(xv, a.y, acc[q].y);
                acc[q].z = fmaf(xv, a.z, acc[q].z);
                acc[q].w = fmaf(xv, a.w, acc[q].w);
            }
        }
        float4* yp = reinterpret_cast<float4*>(Yt + (size_t)i * 64);
#pragma unroll
        for (int q = 0; q < 16; ++q) yp[q] = acc[q];
    }
}

// K3 (fallback when ws can't hold a dedicated Yt): Yt[m][o] = (Wl-Wr)x
__global__ __launch_bounds__(256) void k_y(const float* __restrict__ x,
                                           const float* __restrict__ W,
                                           float* __restrict__ Yt) {
    __shared__ float Al[C_ * 64];
    __shared__ float xl[C_ * 64];
    int tid = threadIdx.x;
    int bid = blockIdx.x;
    int b = bid >> 5;
    int m0 = (bid & 31) * 64;
    {
        int o = tid & 63, cb = tid >> 6;
#pragma unroll
        for (int j = 0; j < 16; ++j) {
            int c = cb * 16 + j;
            Al[c * 64 + o] = W[o * 128 + c] - W[o * 128 + 64 + c];
            xl[c * 64 + o] = x[((size_t)b * C_ + c) * N_ + m0 + o];
        }
    }
    __syncthreads();
    int ml = tid & 63, og = tid >> 6;
    float acc[16];
#pragma unroll
    for (int j = 0; j < 16; ++j) acc[j] = 0.f;
#pragma unroll 4
    for (int c = 0; c < C_; ++c) {
        float xv = xl[c * 64 + ml];
        const float4* a4 = reinterpret_cast<const float4*>(&Al[c * 64 + og * 16]);
#pragma unroll
        for (int q = 0; q < 4; ++q) {
            float4 av = a4[q];
            acc[q*4+0] = fmaf(av.x, xv, acc[q*4+0]);
            acc[q*4+1] = fmaf(av.y, xv, acc[q*4+1]);
            acc[q*4+2] = fmaf(av.z, xv, acc[q*4+2]);
            acc[q*4+3] = fmaf(av.w, xv, acc[q*4+3]);
        }
    }
    float* yp = Yt + ((size_t)b * N_ + m0 + ml) * C_ + og * 16;
#pragma unroll
    for (int q = 0; q < 4; ++q)
        reinterpret_cast<float4*>(yp)[q] =
            make_float4(acc[q*4+0], acc[q*4+1], acc[q*4+2], acc[q*4+3]);
}

// K2a: MFMA distance pass. Identical to r11 except __launch_bounds__(256, 2):
// occupancy is grid-limited at 2 waves/SIMD, so allow the allocator the full
// 256-VGPR budget (r11's 64-VGPR squeeze caused ~2.4x instruction inflation).
__global__ __launch_bounds__(256, 2) void k_dist(const unsigned short* __restrict__ xh,
                                                 const float* __restrict__ sqf,
                                                 unsigned short* __restrict__ candu) {
    __shared__ __align__(16) unsigned short xtl[256 * 64];   // 32 KB
    __shared__ float sqm[256];
    int tid = threadIdx.x;
    int w = tid >> 6, lane = tid & 63;
    int bid = blockIdx.x;             // B_*32 = 512
    int b = bid >> 5;
    int n0 = (bid & 31) * 64;
    const unsigned short* xhb = xh + (size_t)b * N_ * 64;

    {   // stage 64 row-vectors (8 KB): linear coalesced copy (swizzle in xh)
#pragma unroll
        for (int i = 0; i < 2; ++i) {
            int ch = tid + 256 * i;
            *reinterpret_cast<uint4*>(&xtl[ch * 8]) =
                *reinterpret_cast<const uint4*>(&xhb[(size_t)n0 * 64 + ch * 8]);
        }
    }
    __syncthreads();
    int rl = w * 16 + (lane & 15);
    int cb0 = (lane >> 4), cb1 = 4 + (lane >> 4);
    bf16x8 afr0 = *reinterpret_cast<const bf16x8*>(&xtl[rl * 64 + ((cb0 ^ (lane & 7)) * 8)]);
    bf16x8 afr1 = *reinterpret_cast<const bf16x8*>(&xtl[rl * 64 + ((cb1 ^ (lane & 7)) * 8)]);
    float rsq[4];
#pragma unroll
    for (int r = 0; r < 4; ++r)
        rsq[r] = sqf[b * N_ + n0 + w * 16 + (lane >> 4) * 4 + r];

    unsigned list[4][LQ];
#pragma unroll
    for (int r = 0; r < 4; ++r)
#pragma unroll
        for (int j = 0; j < LQ; ++j) list[r][j] = 0xFFFFFFFFu;

    for (int t = 0; t < 8; ++t) {
        int m0 = t * 256;
        __syncthreads();
        {   // stage m-tile 256x64 bf16 (32 KB): linear coalesced copy
#pragma unroll
            for (int i = 0; i < 8; ++i) {
                int ch = tid + 256 * i;
                *reinterpret_cast<uint4*>(&xtl[ch * 8]) =
                    *reinterpret_cast<const uint4*>(&xhb[(size_t)m0 * 64 + ch * 8]);
            }
            sqm[tid] = sqf[b * N_ + m0 + tid];
        }
        __syncthreads();
        // per-lane bases: (mb*16)&7==0 -> swizzle slot is mb-invariant;
        // full unroll gives ds_read_b128 with immediate offsets (zero addr VALU)
        const unsigned short* pB0 = &xtl[(lane & 15) * 64 + ((cb0 ^ (lane & 7)) * 8)];
        const unsigned short* pB1 = &xtl[(lane & 15) * 64 + ((cb1 ^ (lane & 7)) * 8)];
        const float* pS = &sqm[lane & 15];
#pragma unroll
        for (int mb = 0; mb < 16; ++mb) {
            bf16x8 bf0 = *reinterpret_cast<const bf16x8*>(pB0 + mb * 1024);
            bf16x8 bf1 = *reinterpret_cast<const bf16x8*>(pB1 + mb * 1024);
            f32x4 acc = {0.f, 0.f, 0.f, 0.f};
            acc = __builtin_amdgcn_mfma_f32_16x16x32_bf16(afr0, bf0, acc, 0, 0, 0);
            acc = __builtin_amdgcn_mfma_f32_16x16x32_bf16(afr1, bf1, acc, 0, 0, 0);
            float smv = pS[mb * 16];
            unsigned mg = (unsigned)(m0 + mb * 16) | (unsigned)(lane & 15);
#pragma unroll
            for (int r = 0; r < 4; ++r) {
                float rs = rsq[r] + smv;
                float d = fmaf(-2.f, acc[r], rs);
                d = fmaxf(d, 0.f);   // d>=0: IEEE bits are unsigned-monotone
                unsigned key = (__float_as_uint(d) & 0xFFFFF800u) | mg;
#pragma unroll
                for (int j = LQ - 1; j > 0; --j)
                    list[r][j] = umin_(list[r][j], umax_(list[r][j - 1], key));
                list[r][0] = umin_(list[r][0], key);
            }
        }
    }

    // extraction: 24 rounds; all 4 row-groups' shfl chains interleaved (ILP).
    // keys unique (low 11 bits = m, m%16 = lane&15) -> exactly one owner pops.
    size_t grow0 = (size_t)b * N_ + n0 + w * 16 + (lane >> 4) * 4;
#pragma unroll 1
    for (int it = 0; it < CAND; ++it) {
        unsigned head[4], wv[4];
#pragma unroll
        for (int j = 0; j < 4; ++j) { head[j] = list[j][0]; wv[j] = head[j]; }
#pragma unroll
        for (int d2 = 1; d2 < 16; d2 <<= 1)
#pragma unroll
            for (int j = 0; j < 4; ++j)
                wv[j] = umin_(wv[j], (unsigned)__shfl_xor((int)wv[j], d2, 16));
#pragma unroll
        for (int j = 0; j < 4; ++j) {
            bool own = (head[j] == wv[j]);
#pragma unroll
            for (int jj = 0; jj < LQ - 1; ++jj)
                list[j][jj] = own ? list[j][jj + 1] : list[j][jj];
            list[j][LQ - 1] = own ? 0xFFFFFFFFu : list[j][LQ - 1];
            if ((lane & 15) == 0)
                candu[(grow0 + j) * CAND + it] = (unsigned short)(wv[j] & 2047u);
        }
    }
}

// K2b: exact numpy-f32 rescore (sequential c, separate mul/add) + stable rank.
__global__ __launch_bounds__(256) void k_rescore(const float* __restrict__ x,
                                                 const float* __restrict__ xrT,
                                                 const float* __restrict__ sqf,
                                                 const unsigned short* __restrict__ candu,
                                                 float* __restrict__ idxf) {
    int tid = threadIdx.x;
    int w = tid >> 6, lane = tid & 63;
    size_t grow = (size_t)blockIdx.x * 4 + w;   // 0..32767
    int b = (int)(grow >> 11), n = (int)(grow & (N_ - 1));
    float d = 0.f;
    unsigned m = 0xFFFFFFFFu;
    if (xrT) {
        const float* xr = xrT + (size_t)b * N_ * C_;
        const float* xn = xr + (size_t)n * C_;
        if (lane < CAND) {
            m = candu[grow * CAND + lane];
            const float* xm = xr + (size_t)m * C_;
            float a = 0.f;
#pragma unroll 8
            for (int c = 0; c < C_; ++c)
                a = __fadd_rn(a, __fmul_rn(xn[c], xm[c]));
            d = __fadd_rn(__fsub_rn(sqf[b * N_ + n], __fmul_rn(2.0f, a)), sqf[b * N_ + m]);
        }
    } else {
        const float* xb = x + (size_t)b * C_ * N_;
        if (lane < CAND) {
            m = candu[grow * CAND + lane];
            float a = 0.f;
#pragma unroll 8
            for (int c = 0; c < C_; ++c)
                a = __fadd_rn(a, __fmul_rn(xb[(size_t)c * N_ + n], xb[(size_t)c * N_ + m]));
            d = __fadd_rn(__fsub_rn(sqf[b * N_ + n], __fmul_rn(2.0f, a)), sqf[b * N_ + m]);
        }
    }
    int rank = 0;
#pragma unroll 1
    for (int j = 0; j < CAND; ++j) {
        float dj = __shfl(d, j, 64);
        unsigned mj = (unsigned)__shfl((int)m, j, 64);
        if (lane < CAND && (dj < d || (dj == d && mj < m))) ++rank;
    }
    if (lane < CAND && rank < K_)
        idxf[grow * K_ + rank] = (float)m;
}

// K4: out[b][o][n] = leaky( s[o]*(u + max_k Yt[b][idx[n][k]][o]) + t[o] )
__global__ __launch_bounds__(256) void k_out(const float* __restrict__ x,
                                             const float* __restrict__ W,
                                             const float* __restrict__ gamma,
                                             const float* __restrict__ beta,
                                             const float* __restrict__ rmean,
                                             const float* __restrict__ rvar,
                                             const float* __restrict__ Yt,
                                             const float* __restrict__ idxf,
                                             float* __restrict__ out) {
    __shared__ float Bl[C_ * 64];
    __shared__ float xl[C_ * 64];
    __shared__ float resl[64 * 65];
    __shared__ float sl[64], tl[64];
    int tid = threadIdx.x;
    int bid = blockIdx.x;
    int b = bid >> 5;
    int n0 = (bid & 31) * 64;
    {
        int o = tid & 63, cb = tid >> 6;
#pragma unroll
        for (int j = 0; j < 16; ++j) {
            int c = cb * 16 + j;
            Bl[c * 64 + o] = W[o * 128 + 64 + c];
            xl[c * 64 + o] = x[((size_t)b * C_ + c) * N_ + n0 + o];
        }
        if (tid < 64) {
            float s = gamma[tid] / sqrtf(rvar[tid] + 1e-5f);
            sl[tid] = s;
            tl[tid] = beta[tid] - rmean[tid] * s;
        }
    }
    __syncthreads();
    int w = tid >> 6, o = tid & 63;
    for (int i = 0; i < 16; ++i) {
        int nl = w * 16 + i;
        int n = n0 + nl;
        float u = 0.f;
#pragma unroll 8
        for (int c = 0; c < C_; ++c)
            u = fmaf(Bl[c * 64 + o], xl[c * 64 + nl], u);
        const float* ip = idxf + ((size_t)b * N_ + n) * K_;
        float v = -3.4e38f;
#pragma unroll
        for (int k = 0; k < K_; ++k) {
            int mi = (int)ip[k];
            v = fmaxf(v, Yt[((size_t)b * N_ + mi) * C_ + o]);
        }
        float h = u + v;
        float val = sl[o] * h + tl[o];
        val = val > 0.f ? val : 0.2f * val;
        resl[o * 65 + nl] = val;
    }
    __syncthreads();
    {
        int nl = tid & 63, ob = tid >> 6;
#pragma unroll
        for (int j = 0; j < 16; ++j) {
            int o2 = ob * 16 + j;
            out[((size_t)b * C_ + o2) * N_ + n0 + nl] = resl[o2 * 65 + nl];
        }
    }
}

extern "C" void kernel_launch(void* const* d_in, const int* in_sizes, int n_in,
                              void* d_out, int out_size, void* d_ws, size_t ws_size,
                              hipStream_t stream) {
    const float* x     = (const float*)d_in[0];
    const float* W     = (const float*)d_in[1];
    const float* gamma = (const float*)d_in[2];
    const float* beta  = (const float*)d_in[3];
    const float* rmean = (const float*)d_in[4];
    const float* rvar  = (const float*)d_in[5];

    float* out  = (float*)d_out;                         // [16][64][2048]
    float* idxf = out + (size_t)B_ * C_ * N_;            // [16][2048][20] as floats

    char* ws = (char*)d_ws;
    // layout: sqf 128K | candu u16x24 1.5M | xh 4M | xrT 8M | [Yt 8M if room]
    float* sqf            = (float*)ws;
    unsigned short* candu = (unsigned short*)(ws + 131072);
    unsigned short* xh    = (unsigned short*)(ws + 131072 + 1572864);
    size_t off_xrT        = 131072 + 1572864 + 4194304;              // 5.90 MB
    size_t need_xrT       = off_xrT + 8388608;                       // 14.28 MB (< r9-proven 15.86)
    size_t need_fused     = need_xrT + 8388608;                      // 22.68 MB
    float* xrT            = (ws_size >= need_xrT) ? (float*)(ws + off_xrT) : nullptr;
    bool fused            = (ws_size >= need_fused);
    // fallback Yt aliases candu+xh+xrT-head (all dead before k_y runs)
    float* Yt             = fused ? (float*)(ws + need_xrT) : (float*)(ws + 131072);

    k_sq     <<<B_ * N_ / 128, 128, 0, stream>>>(x, sqf, xh, xrT, fused ? Yt : nullptr, W);
    k_dist   <<<B_ * 32, 256, 0, stream>>>(xh, sqf, candu);
    k_rescore<<<B_ * N_ / 4, 256, 0, stream>>>(x, xrT, sqf, candu, idxf);
    if (!fused)
        k_y  <<<B_ * (N_ / 64), 256, 0, stream>>>(x, W, Yt);
    k_out    <<<B_ * (N_ / 64), 256, 0, stream>>>(x, W, gamma, beta, rmean, rvar, Yt, idxf, out);
}

// Round 13
// 176.375 us; speedup vs baseline: 1.2659x; 1.1238x over previous
//
#include <hip/hip_runtime.h>
#include <cstdint>
#include <cstddef>

#define B_ 16
#define C_ 64
#define N_ 2048
#define K_ 20
#define CAND 24
#define LQ 12

typedef short bf16x8 __attribute__((ext_vector_type(8)));
typedef float f32x4 __attribute__((ext_vector_type(4)));

__device__ __forceinline__ unsigned umin_(unsigned a, unsigned b) { return a < b ? a : b; }
__device__ __forceinline__ unsigned umax_(unsigned a, unsigned b) { return a > b ? a : b; }
__device__ __forceinline__ unsigned short bfr_(float v) {
    unsigned u = __float_as_uint(v);
    return (unsigned short)((u + 0x7FFFu + ((u >> 16) & 1u)) >> 16);
}

// K1: sqf = np.sum(xt*xt,-1) bit-exact (pairwise 8-acc tree);
// xh = bf16 rows, c-blocks XOR-swizzled (block cb at slot cb^(n&7));
// xrT = f32 contiguous rows for the exact rescore;
// optional fused Y: Yt[n][o] = sum_c (Wl-Wr)[o][c] * x[c][n]  (ws-gated).
__global__ __launch_bounds__(128) void k_sq(const float* __restrict__ x,
                                            float* __restrict__ sqf,
                                            unsigned short* __restrict__ xh,
                                            float* __restrict__ xrT,
                                            float* __restrict__ Yt,
                                            const float* __restrict__ W) {
    __shared__ float Ag[C_ * 64];   // [c][o]
    int tid = threadIdx.x;
    bool doY = (Yt != nullptr);
    if (doY) {
        int o = tid & 63, ch = tid >> 6;
#pragma unroll
        for (int j = 0; j < 32; ++j) {
            int c = ch * 32 + j;
            Ag[c * 64 + o] = W[o * 128 + c] - W[o * 128 + 64 + c];
        }
    }
    int i = blockIdx.x * 128 + tid;   // 0..B_*N_-1
    int b = i >> 11, n = i & (N_ - 1);
    const float* xb = x + (size_t)b * C_ * N_ + n;
    float vr[C_];
#pragma unroll
    for (int c = 0; c < C_; ++c) vr[c] = xb[(size_t)c * N_];
    float p[C_];
#pragma unroll
    for (int c = 0; c < C_; ++c) p[c] = __fmul_rn(vr[c], vr[c]);
    float r[8];
#pragma unroll
    for (int k = 0; k < 8; ++k) r[k] = p[k];
#pragma unroll
    for (int ii = 8; ii < 64; ii += 8) {
#pragma unroll
        for (int k = 0; k < 8; ++k) r[k] = __fadd_rn(r[k], p[ii + k]);
    }
    float s0 = __fadd_rn(__fadd_rn(r[0], r[1]), __fadd_rn(r[2], r[3]));
    float s1 = __fadd_rn(__fadd_rn(r[4], r[5]), __fadd_rn(r[6], r[7]));
    sqf[i] = __fadd_rn(s0, s1);

    unsigned short* xrow = xh + (size_t)i * 64;
#pragma unroll
    for (int cb = 0; cb < 8; ++cb) {
        bf16x8 pk;
#pragma unroll
        for (int e = 0; e < 8; ++e) pk[e] = (short)bfr_(vr[cb * 8 + e]);
        *reinterpret_cast<bf16x8*>(xrow + ((cb ^ (n & 7)) * 8)) = pk;
    }
    if (xrT) {
        float4* dst = reinterpret_cast<float4*>(xrT + (size_t)i * C_);
#pragma unroll
        for (int q = 0; q < 16; ++q)
            dst[q] = make_float4(vr[q*4+0], vr[q*4+1], vr[q*4+2], vr[q*4+3]);
    }
    if (doY) {
        __syncthreads();
        float4 acc[16];
#pragma unroll
        for (int q = 0; q < 16; ++q) acc[q] = make_float4(0.f, 0.f, 0.f, 0.f);
#pragma unroll 4
        for (int c = 0; c < C_; ++c) {
            float xv = vr[c];
            const float4* a4 = reinterpret_cast<const float4*>(&Ag[c * 64]);
#pragma unroll
            for (int q = 0; q < 16; ++q) {
                float4 a = a4[q];
                acc[q].x = fmaf(xv, a.x, acc[q].x);
                acc[q].y = fmaf(xv, a.y, acc[q].y);
                acc[q].z = fmaf(xv, a.z, acc[q].z);
                acc[q].w = fmaf(xv, a.w, acc[q].w);
            }
        }
        float4* yp = reinterpret_cast<float4*>(Yt + (size_t)i * 64);
#pragma unroll
        for (int q = 0; q < 16; ++q) yp[q] = acc[q];
    }
}

// K3 (fallback when ws can't hold a dedicated Yt): Yt[m][o] = (Wl-Wr)x
__global__ __launch_bounds__(256) void k_y(const float* __restrict__ x,
                                           const float* __restrict__ W,
                                           float* __restrict__ Yt) {
    __shared__ float Al[C_ * 64];
    __shared__ float xl[C_ * 64];
    int tid = threadIdx.x;
    int bid = blockIdx.x;
    int b = bid >> 5;
    int m0 = (bid & 31) * 64;
    {
        int o = tid & 63, cb = tid >> 6;
#pragma unroll
        for (int j = 0; j < 16; ++j) {
            int c = cb * 16 + j;
            Al[c * 64 + o] = W[o * 128 + c] - W[o * 128 + 64 + c];
            xl[c * 64 + o] = x[((size_t)b * C_ + c) * N_ + m0 + o];
        }
    }
    __syncthreads();
    int ml = tid & 63, og = tid >> 6;
    float acc[16];
#pragma unroll
    for (int j = 0; j < 16; ++j) acc[j] = 0.f;
#pragma unroll 4
    for (int c = 0; c < C_; ++c) {
        float xv = xl[c * 64 + ml];
        const float4* a4 = reinterpret_cast<const float4*>(&Al[c * 64 + og * 16]);
#pragma unroll
        for (int q = 0; q < 4; ++q) {
            float4 av = a4[q];
            acc[q*4+0] = fmaf(av.x, xv, acc[q*4+0]);
            acc[q*4+1] = fmaf(av.y, xv, acc[q*4+1]);
            acc[q*4+2] = fmaf(av.z, xv, acc[q*4+2]);
            acc[q*4+3] = fmaf(av.w, xv, acc[q*4+3]);
        }
    }
    float* yp = Yt + ((size_t)b * N_ + m0 + ml) * C_ + og * 16;
#pragma unroll
    for (int q = 0; q < 4; ++q)
        reinterpret_cast<float4*>(yp)[q] =
            make_float4(acc[q*4+0], acc[q*4+1], acc[q*4+2], acc[q*4+3]);
}

// K2a: MFMA distance pass. r12 structure, but the sorted-insert step is a
// single v_med3_u32 (median == min(l[j], max(l[j-1], key)) given sortedness)
// via inline asm with "+v" constraints -> halves insert ops AND pins the
// lists into arch VGPRs (defeats the AGPR-copy inflation seen in r11/r12).
__global__ __launch_bounds__(256, 2) void k_dist(const unsigned short* __restrict__ xh,
                                                 const float* __restrict__ sqf,
                                                 unsigned short* __restrict__ candu) {
    __shared__ __align__(16) unsigned short xtl[256 * 64];   // 32 KB
    __shared__ float sqm[256];
    int tid = threadIdx.x;
    int w = tid >> 6, lane = tid & 63;
    int bid = blockIdx.x;             // B_*32 = 512
    int b = bid >> 5;
    int n0 = (bid & 31) * 64;
    const unsigned short* xhb = xh + (size_t)b * N_ * 64;

    {   // stage 64 row-vectors (8 KB): linear coalesced copy (swizzle in xh)
#pragma unroll
        for (int i = 0; i < 2; ++i) {
            int ch = tid + 256 * i;
            *reinterpret_cast<uint4*>(&xtl[ch * 8]) =
                *reinterpret_cast<const uint4*>(&xhb[(size_t)n0 * 64 + ch * 8]);
        }
    }
    __syncthreads();
    int rl = w * 16 + (lane & 15);
    int cb0 = (lane >> 4), cb1 = 4 + (lane >> 4);
    bf16x8 afr0 = *reinterpret_cast<const bf16x8*>(&xtl[rl * 64 + ((cb0 ^ (lane & 7)) * 8)]);
    bf16x8 afr1 = *reinterpret_cast<const bf16x8*>(&xtl[rl * 64 + ((cb1 ^ (lane & 7)) * 8)]);
    float rsq[4];
#pragma unroll
    for (int r = 0; r < 4; ++r)
        rsq[r] = sqf[b * N_ + n0 + w * 16 + (lane >> 4) * 4 + r];

    unsigned list[4][LQ];
#pragma unroll
    for (int r = 0; r < 4; ++r)
#pragma unroll
        for (int j = 0; j < LQ; ++j) list[r][j] = 0xFFFFFFFFu;

    for (int t = 0; t < 8; ++t) {
        int m0 = t * 256;
        __syncthreads();
        {   // stage m-tile 256x64 bf16 (32 KB): linear coalesced copy
#pragma unroll
            for (int i = 0; i < 8; ++i) {
                int ch = tid + 256 * i;
                *reinterpret_cast<uint4*>(&xtl[ch * 8]) =
                    *reinterpret_cast<const uint4*>(&xhb[(size_t)m0 * 64 + ch * 8]);
            }
            sqm[tid] = sqf[b * N_ + m0 + tid];
        }
        __syncthreads();
        // per-lane bases: (mb*16)&7==0 -> swizzle slot is mb-invariant;
        // full unroll gives ds_read_b128 with immediate offsets (zero addr VALU)
        const unsigned short* pB0 = &xtl[(lane & 15) * 64 + ((cb0 ^ (lane & 7)) * 8)];
        const unsigned short* pB1 = &xtl[(lane & 15) * 64 + ((cb1 ^ (lane & 7)) * 8)];
        const float* pS = &sqm[lane & 15];
#pragma unroll
        for (int mb = 0; mb < 16; ++mb) {
            bf16x8 bf0 = *reinterpret_cast<const bf16x8*>(pB0 + mb * 1024);
            bf16x8 bf1 = *reinterpret_cast<const bf16x8*>(pB1 + mb * 1024);
            f32x4 acc = {0.f, 0.f, 0.f, 0.f};
            acc = __builtin_amdgcn_mfma_f32_16x16x32_bf16(afr0, bf0, acc, 0, 0, 0);
            acc = __builtin_amdgcn_mfma_f32_16x16x32_bf16(afr1, bf1, acc, 0, 0, 0);
            float smv = pS[mb * 16];
            unsigned mg = (unsigned)(m0 + mb * 16) | (unsigned)(lane & 15);
#pragma unroll
            for (int r = 0; r < 4; ++r) {
                float rs = rsq[r] + smv;
                float d = fmaf(-2.f, acc[r], rs);
                d = fmaxf(d, 0.f);   // d>=0: IEEE bits are unsigned-monotone
                unsigned key = (__float_as_uint(d) & 0xFFFFF800u) | mg;
                // branchless sorted insert: l[j] = med3(l[j], l[j-1], key)
                // (median == min(l[j], max(l[j-1], key)) since l[j] >= l[j-1])
#pragma unroll
                for (int j = LQ - 1; j > 0; --j)
                    asm("v_med3_u32 %0, %0, %1, %2"
                        : "+v"(list[r][j])
                        : "v"(list[r][j - 1]), "v"(key));
                list[r][0] = umin_(list[r][0], key);
            }
        }
    }

    // extraction: 24 rounds; all 4 row-groups' shfl chains interleaved (ILP).
    // keys unique (low 11 bits = m, m%16 = lane&15) -> exactly one owner pops.
    size_t grow0 = (size_t)b * N_ + n0 + w * 16 + (lane >> 4) * 4;
#pragma unroll 1
    for (int it = 0; it < CAND; ++it) {
        unsigned head[4], wv[4];
#pragma unroll
        for (int j = 0; j < 4; ++j) { head[j] = list[j][0]; wv[j] = head[j]; }
#pragma unroll
        for (int d2 = 1; d2 < 16; d2 <<= 1)
#pragma unroll
            for (int j = 0; j < 4; ++j)
                wv[j] = umin_(wv[j], (unsigned)__shfl_xor((int)wv[j], d2, 16));
#pragma unroll
        for (int j = 0; j < 4; ++j) {
            bool own = (head[j] == wv[j]);
#pragma unroll
            for (int jj = 0; jj < LQ - 1; ++jj)
                list[j][jj] = own ? list[j][jj + 1] : list[j][jj];
            list[j][LQ - 1] = own ? 0xFFFFFFFFu : list[j][LQ - 1];
            if ((lane & 15) == 0)
                candu[(grow0 + j) * CAND + it] = (unsigned short)(wv[j] & 2047u);
        }
    }
}

// K2b: exact numpy-f32 rescore (sequential c, separate mul/add) + stable rank.
__global__ __launch_bounds__(256) void k_rescore(const float* __restrict__ x,
                                                 const float* __restrict__ xrT,
                                                 const float* __restrict__ sqf,
                                                 const unsigned short* __restrict__ candu,
                                                 float* __restrict__ idxf) {
    int tid = threadIdx.x;
    int w = tid >> 6, lane = tid & 63;
    size_t grow = (size_t)blockIdx.x * 4 + w;   // 0..32767
    int b = (int)(grow >> 11), n = (int)(grow & (N_ - 1));
    float d = 0.f;
    unsigned m = 0xFFFFFFFFu;
    if (xrT) {
        const float* xr = xrT + (size_t)b * N_ * C_;
        const float* xn = xr + (size_t)n * C_;
        if (lane < CAND) {
            m = candu[grow * CAND + lane];
            const float* xm = xr + (size_t)m * C_;
            float a = 0.f;
#pragma unroll 8
            for (int c = 0; c < C_; ++c)
                a = __fadd_rn(a, __fmul_rn(xn[c], xm[c]));
            d = __fadd_rn(__fsub_rn(sqf[b * N_ + n], __fmul_rn(2.0f, a)), sqf[b * N_ + m]);
        }
    } else {
        const float* xb = x + (size_t)b * C_ * N_;
        if (lane < CAND) {
            m = candu[grow * CAND + lane];
            float a = 0.f;
#pragma unroll 8
            for (int c = 0; c < C_; ++c)
                a = __fadd_rn(a, __fmul_rn(xb[(size_t)c * N_ + n], xb[(size_t)c * N_ + m]));
            d = __fadd_rn(__fsub_rn(sqf[b * N_ + n], __fmul_rn(2.0f, a)), sqf[b * N_ + m]);
        }
    }
    int rank = 0;
#pragma unroll 1
    for (int j = 0; j < CAND; ++j) {
        float dj = __shfl(d, j, 64);
        unsigned mj = (unsigned)__shfl((int)m, j, 64);
        if (lane < CAND && (dj < d || (dj == d && mj < m))) ++rank;
    }
    if (lane < CAND && rank < K_)
        idxf[grow * K_ + rank] = (float)m;
}

// K4: out[b][o][n] = leaky( s[o]*(u + max_k Yt[b][idx[n][k]][o]) + t[o] )
__global__ __launch_bounds__(256) void k_out(const float* __restrict__ x,
                                             const float* __restrict__ W,
                                             const float* __restrict__ gamma,
                                             const float* __restrict__ beta,
                                             const float* __restrict__ rmean,
                                             const float* __restrict__ rvar,
                                             const float* __restrict__ Yt,
                                             const float* __restrict__ idxf,
                                             float* __restrict__ out) {
    __shared__ float Bl[C_ * 64];
    __shared__ float xl[C_ * 64];
    __shared__ float resl[64 * 65];
    __shared__ float sl[64], tl[64];
    int tid = threadIdx.x;
    int bid = blockIdx.x;
    int b = bid >> 5;
    int n0 = (bid & 31) * 64;
    {
        int o = tid & 63, cb = tid >> 6;
#pragma unroll
        for (int j = 0; j < 16; ++j) {
            int c = cb * 16 + j;
            Bl[c * 64 + o] = W[o * 128 + 64 + c];
            xl[c * 64 + o] = x[((size_t)b * C_ + c) * N_ + n0 + o];
        }
        if (tid < 64) {
            float s = gamma[tid] / sqrtf(rvar[tid] + 1e-5f);
            sl[tid] = s;
            tl[tid] = beta[tid] - rmean[tid] * s;
        }
    }
    __syncthreads();
    int w = tid >> 6, o = tid & 63;
    for (int i = 0; i < 16; ++i) {
        int nl = w * 16 + i;
        int n = n0 + nl;
        float u = 0.f;
#pragma unroll 8
        for (int c = 0; c < C_; ++c)
            u = fmaf(Bl[c * 64 + o], xl[c * 64 + nl], u);
        const float* ip = idxf + ((size_t)b * N_ + n) * K_;
        float v = -3.4e38f;
#pragma unroll
        for (int k = 0; k < K_; ++k) {
            int mi = (int)ip[k];
            v = fmaxf(v, Yt[((size_t)b * N_ + mi) * C_ + o]);
        }
        float h = u + v;
        float val = sl[o] * h + tl[o];
        val = val > 0.f ? val : 0.2f * val;
        resl[o * 65 + nl] = val;
    }
    __syncthreads();
    {
        int nl = tid & 63, ob = tid >> 6;
#pragma unroll
        for (int j = 0; j < 16; ++j) {
            int o2 = ob * 16 + j;
            out[((size_t)b * C_ + o2) * N_ + n0 + nl] = resl[o2 * 65 + nl];
        }
    }
}

extern "C" void kernel_launch(void* const* d_in, const int* in_sizes, int n_in,
                              void* d_out, int out_size, void* d_ws, size_t ws_size,
                              hipStream_t stream) {
    const float* x     = (const float*)d_in[0];
    const float* W     = (const float*)d_in[1];
    const float* gamma = (const float*)d_in[2];
    const float* beta  = (const float*)d_in[3];
    const float* rmean = (const float*)d_in[4];
    const float* rvar  = (const float*)d_in[5];

    float* out  = (float*)d_out;                         // [16][64][2048]
    float* idxf = out + (size_t)B_ * C_ * N_;            // [16][2048][20] as floats

    char* ws = (char*)d_ws;
    // layout: sqf 128K | candu u16x24 1.5M | xh 4M | xrT 8M | [Yt 8M if room]
    float* sqf            = (float*)ws;
    unsigned short* candu = (unsigned short*)(ws + 131072);
    unsigned short* xh    = (unsigned short*)(ws + 131072 + 1572864);
    size_t off_xrT        = 131072 + 1572864 + 4194304;              // 5.90 MB
    size_t need_xrT       = off_xrT + 8388608;                       // 14.28 MB (< r9-proven 15.86)
    size_t need_fused     = need_xrT + 8388608;                      // 22.68 MB
    float* xrT            = (ws_size >= need_xrT) ? (float*)(ws + off_xrT) : nullptr;
    bool fused            = (ws_size >= need_fused);
    // fallback Yt aliases candu+xh+xrT-head (all dead before k_y runs)
    float* Yt             = fused ? (float*)(ws + need_xrT) : (float*)(ws + 131072);

    k_sq     <<<B_ * N_ / 128, 128, 0, stream>>>(x, sqf, xh, xrT, fused ? Yt : nullptr, W);
    k_dist   <<<B_ * 32, 256, 0, stream>>>(xh, sqf, candu);
    k_rescore<<<B_ * N_ / 4, 256, 0, stream>>>(x, xrT, sqf, candu, idxf);
    if (!fused)
        k_y  <<<B_ * (N_ / 64), 256, 0, stream>>>(x, W, Yt);
    k_out    <<<B_ * (N_ / 64), 256, 0, stream>>>(x, W, gamma, beta, rmean, rvar, Yt, idxf, out);
}

// Round 14
// 174.560 us; speedup vs baseline: 1.2790x; 1.0104x over previous
//
#include <hip/hip_runtime.h>
#include <cstdint>
#include <cstddef>

#define B_ 16
#define C_ 64
#define N_ 2048
#define K_ 20
#define CAND 24
#define LQ 12

typedef short bf16x8 __attribute__((ext_vector_type(8)));
typedef float f32x4 __attribute__((ext_vector_type(4)));

__device__ __forceinline__ unsigned umin_(unsigned a, unsigned b) { return a < b ? a : b; }
__device__ __forceinline__ unsigned umax_(unsigned a, unsigned b) { return a > b ? a : b; }
__device__ __forceinline__ unsigned short bfr_(float v) {
    unsigned u = __float_as_uint(v);
    return (unsigned short)((u + 0x7FFFu + ((u >> 16) & 1u)) >> 16);
}

// K1: sqf = np.sum(xt*xt,-1) bit-exact (pairwise 8-acc tree);
// xh = bf16 rows, c-blocks XOR-swizzled (block cb at slot cb^(n&7));
// xrT = f32 contiguous rows for the exact rescore;
// optional fused Y: Yt[n][o] = sum_c (Wl-Wr)[o][c] * x[c][n]  (ws-gated).
__global__ __launch_bounds__(128) void k_sq(const float* __restrict__ x,
                                            float* __restrict__ sqf,
                                            unsigned short* __restrict__ xh,
                                            float* __restrict__ xrT,
                                            float* __restrict__ Yt,
                                            const float* __restrict__ W) {
    __shared__ float Ag[C_ * 64];   // [c][o]
    int tid = threadIdx.x;
    bool doY = (Yt != nullptr);
    if (doY) {
        int o = tid & 63, ch = tid >> 6;
#pragma unroll
        for (int j = 0; j < 32; ++j) {
            int c = ch * 32 + j;
            Ag[c * 64 + o] = W[o * 128 + c] - W[o * 128 + 64 + c];
        }
    }
    int i = blockIdx.x * 128 + tid;   // 0..B_*N_-1
    int b = i >> 11, n = i & (N_ - 1);
    const float* xb = x + (size_t)b * C_ * N_ + n;
    float vr[C_];
#pragma unroll
    for (int c = 0; c < C_; ++c) vr[c] = xb[(size_t)c * N_];
    float p[C_];
#pragma unroll
    for (int c = 0; c < C_; ++c) p[c] = __fmul_rn(vr[c], vr[c]);
    float r[8];
#pragma unroll
    for (int k = 0; k < 8; ++k) r[k] = p[k];
#pragma unroll
    for (int ii = 8; ii < 64; ii += 8) {
#pragma unroll
        for (int k = 0; k < 8; ++k) r[k] = __fadd_rn(r[k], p[ii + k]);
    }
    float s0 = __fadd_rn(__fadd_rn(r[0], r[1]), __fadd_rn(r[2], r[3]));
    float s1 = __fadd_rn(__fadd_rn(r[4], r[5]), __fadd_rn(r[6], r[7]));
    sqf[i] = __fadd_rn(s0, s1);

    unsigned short* xrow = xh + (size_t)i * 64;
#pragma unroll
    for (int cb = 0; cb < 8; ++cb) {
        bf16x8 pk;
#pragma unroll
        for (int e = 0; e < 8; ++e) pk[e] = (short)bfr_(vr[cb * 8 + e]);
        *reinterpret_cast<bf16x8*>(xrow + ((cb ^ (n & 7)) * 8)) = pk;
    }
    if (xrT) {
        float4* dst = reinterpret_cast<float4*>(xrT + (size_t)i * C_);
#pragma unroll
        for (int q = 0; q < 16; ++q)
            dst[q] = make_float4(vr[q*4+0], vr[q*4+1], vr[q*4+2], vr[q*4+3]);
    }
    if (doY) {
        __syncthreads();
        float4 acc[16];
#pragma unroll
        for (int q = 0; q < 16; ++q) acc[q] = make_float4(0.f, 0.f, 0.f, 0.f);
#pragma unroll 4
        for (int c = 0; c < C_; ++c) {
            float xv = vr[c];
            const float4* a4 = reinterpret_cast<const float4*>(&Ag[c * 64]);
#pragma unroll
            for (int q = 0; q < 16; ++q) {
                float4 a = a4[q];
                acc[q].x = fmaf(xv, a.x, acc[q].x);
                acc[q].y = fmaf(xv, a.y, acc[q].y);
                acc[q].z = fmaf(xv, a.z, acc[q].z);
                acc[q].w = fmaf(xv, a.w, acc[q].w);
            }
        }
        float4* yp = reinterpret_cast<float4*>(Yt + (size_t)i * 64);
#pragma unroll
        for (int q = 0; q < 16; ++q) yp[q] = acc[q];
    }
}

// K3 (fallback when ws can't hold a dedicated Yt): Yt[m][o] = (Wl-Wr)x
__global__ __launch_bounds__(256) void k_y(const float* __restrict__ x,
                                           const float* __restrict__ W,
                                           float* __restrict__ Yt) {
    __shared__ float Al[C_ * 64];
    __shared__ float xl[C_ * 64];
    int tid = threadIdx.x;
    int bid = blockIdx.x;
    int b = bid >> 5;
    int m0 = (bid & 31) * 64;
    {
        int o = tid & 63, cb = tid >> 6;
#pragma unroll
        for (int j = 0; j < 16; ++j) {
            int c = cb * 16 + j;
            Al[c * 64 + o] = W[o * 128 + c] - W[o * 128 + 64 + c];
            xl[c * 64 + o] = x[((size_t)b * C_ + c) * N_ + m0 + o];
        }
    }
    __syncthreads();
    int ml = tid & 63, og = tid >> 6;
    float acc[16];
#pragma unroll
    for (int j = 0; j < 16; ++j) acc[j] = 0.f;
#pragma unroll 4
    for (int c = 0; c < C_; ++c) {
        float xv = xl[c * 64 + ml];
        const float4* a4 = reinterpret_cast<const float4*>(&Al[c * 64 + og * 16]);
#pragma unroll
        for (int q = 0; q < 4; ++q) {
            float4 av = a4[q];
            acc[q*4+0] = fmaf(av.x, xv, acc[q*4+0]);
            acc[q*4+1] = fmaf(av.y, xv, acc[q*4+1]);
            acc[q*4+2] = fmaf(av.z, xv, acc[q*4+2]);
            acc[q*4+3] = fmaf(av.w, xv, acc[q*4+3]);
        }
    }
    float* yp = Yt + ((size_t)b * N_ + m0 + ml) * C_ + og * 16;
#pragma unroll
    for (int q = 0; q < 4; ++q)
        reinterpret_cast<float4*>(yp)[q] =
            make_float4(acc[q*4+0], acc[q*4+1], acc[q*4+2], acc[q*4+3]);
}

// K2: MFMA distance pass + in-kernel exact rescore (fused when xrT present).
// Selection loop identical to r13 (med3 sorted-insert). Tail: candidates to
// LDS -> stage exact f32 rows (aliasing xtl) -> exact numpy-f32 dots ->
// exact stable rank -> write idxf directly. No candu round-trip.
__global__ __launch_bounds__(256, 2) void k_dist(const unsigned short* __restrict__ xh,
                                                 const float* __restrict__ sqf,
                                                 const float* __restrict__ xrT,
                                                 float* __restrict__ idxf,
                                                 unsigned short* __restrict__ candu) {
    __shared__ __align__(16) unsigned short xtl[256 * 64];   // 32 KB
    __shared__ float sqm[256];
    __shared__ unsigned short cl[64][CAND];                  // 3 KB
    __shared__ float dl2[64][CAND];                          // 6 KB
    int tid = threadIdx.x;
    int w = tid >> 6, lane = tid & 63;
    int bid = blockIdx.x;             // B_*32 = 512
    int b = bid >> 5;
    int n0 = (bid & 31) * 64;
    const unsigned short* xhb = xh + (size_t)b * N_ * 64;

    {   // stage 64 row-vectors (8 KB): linear coalesced copy (swizzle in xh)
#pragma unroll
        for (int i = 0; i < 2; ++i) {
            int ch = tid + 256 * i;
            *reinterpret_cast<uint4*>(&xtl[ch * 8]) =
                *reinterpret_cast<const uint4*>(&xhb[(size_t)n0 * 64 + ch * 8]);
        }
    }
    __syncthreads();
    int rl = w * 16 + (lane & 15);
    int cb0 = (lane >> 4), cb1 = 4 + (lane >> 4);
    bf16x8 afr0 = *reinterpret_cast<const bf16x8*>(&xtl[rl * 64 + ((cb0 ^ (lane & 7)) * 8)]);
    bf16x8 afr1 = *reinterpret_cast<const bf16x8*>(&xtl[rl * 64 + ((cb1 ^ (lane & 7)) * 8)]);
    float rsq[4];
#pragma unroll
    for (int r = 0; r < 4; ++r)
        rsq[r] = sqf[b * N_ + n0 + w * 16 + (lane >> 4) * 4 + r];

    unsigned list[4][LQ];
#pragma unroll
    for (int r = 0; r < 4; ++r)
#pragma unroll
        for (int j = 0; j < LQ; ++j) list[r][j] = 0xFFFFFFFFu;

    for (int t = 0; t < 8; ++t) {
        int m0 = t * 256;
        __syncthreads();
        {   // stage m-tile 256x64 bf16 (32 KB): linear coalesced copy
#pragma unroll
            for (int i = 0; i < 8; ++i) {
                int ch = tid + 256 * i;
                *reinterpret_cast<uint4*>(&xtl[ch * 8]) =
                    *reinterpret_cast<const uint4*>(&xhb[(size_t)m0 * 64 + ch * 8]);
            }
            sqm[tid] = sqf[b * N_ + m0 + tid];
        }
        __syncthreads();
        const unsigned short* pB0 = &xtl[(lane & 15) * 64 + ((cb0 ^ (lane & 7)) * 8)];
        const unsigned short* pB1 = &xtl[(lane & 15) * 64 + ((cb1 ^ (lane & 7)) * 8)];
        const float* pS = &sqm[lane & 15];
#pragma unroll
        for (int mb = 0; mb < 16; ++mb) {
            bf16x8 bf0 = *reinterpret_cast<const bf16x8*>(pB0 + mb * 1024);
            bf16x8 bf1 = *reinterpret_cast<const bf16x8*>(pB1 + mb * 1024);
            f32x4 acc = {0.f, 0.f, 0.f, 0.f};
            acc = __builtin_amdgcn_mfma_f32_16x16x32_bf16(afr0, bf0, acc, 0, 0, 0);
            acc = __builtin_amdgcn_mfma_f32_16x16x32_bf16(afr1, bf1, acc, 0, 0, 0);
            float smv = pS[mb * 16];
            unsigned mg = (unsigned)(m0 + mb * 16) | (unsigned)(lane & 15);
#pragma unroll
            for (int r = 0; r < 4; ++r) {
                float rs = rsq[r] + smv;
                float d = fmaf(-2.f, acc[r], rs);
                d = fmaxf(d, 0.f);
                unsigned key = (__float_as_uint(d) & 0xFFFFF800u) | mg;
#pragma unroll
                for (int j = LQ - 1; j > 0; --j)
                    asm("v_med3_u32 %0, %0, %1, %2"
                        : "+v"(list[r][j])
                        : "v"(list[r][j - 1]), "v"(key));
                list[r][0] = umin_(list[r][0], key);
            }
        }
    }

    // extraction: 24 rounds; 4 row-groups' shfl chains interleaved.
    int rowl0 = w * 16 + (lane >> 4) * 4;
    size_t grow0 = (size_t)b * N_ + n0 + rowl0;
    bool fusedR = (xrT != nullptr);
#pragma unroll 1
    for (int it = 0; it < CAND; ++it) {
        unsigned head[4], wv[4];
#pragma unroll
        for (int j = 0; j < 4; ++j) { head[j] = list[j][0]; wv[j] = head[j]; }
#pragma unroll
        for (int d2 = 1; d2 < 16; d2 <<= 1)
#pragma unroll
            for (int j = 0; j < 4; ++j)
                wv[j] = umin_(wv[j], (unsigned)__shfl_xor((int)wv[j], d2, 16));
#pragma unroll
        for (int j = 0; j < 4; ++j) {
            bool own = (head[j] == wv[j]);
#pragma unroll
            for (int jj = 0; jj < LQ - 1; ++jj)
                list[j][jj] = own ? list[j][jj + 1] : list[j][jj];
            list[j][LQ - 1] = own ? 0xFFFFFFFFu : list[j][LQ - 1];
            if ((lane & 15) == 0) {
                if (fusedR) cl[rowl0 + j][it] = (unsigned short)(wv[j] & 2047u);
                else        candu[(grow0 + j) * CAND + it] = (unsigned short)(wv[j] & 2047u);
            }
        }
    }

    if (!fusedR) return;

    // ---- fused exact rescore (numpy-f32, r3-proven formula) ----
    __syncthreads();                       // all waves done with xtl
    float* xnl = reinterpret_cast<float*>(xtl);   // reuse: 64 rows x 64 f32 (16 KB)
    const float* xr = xrT + (size_t)b * N_ * C_;
    {
        const float4* src = reinterpret_cast<const float4*>(xr + (size_t)n0 * C_);
#pragma unroll
        for (int q = 0; q < 4; ++q) {
            int idx = tid + q * 256;       // 1024 float4s
            reinterpret_cast<float4*>(xnl)[idx] = src[idx];
        }
    }
    __syncthreads();
    int bN = b * N_;
#pragma unroll 1
    for (int t2 = 0; t2 < 6; ++t2) {
        int task = tid + t2 * 256;         // 0..1535
        int row = task / 24, ci = task - row * 24;
        int m = cl[row][ci];
        const float* xn = xnl + row * 64;
        const float* xm = xr + (size_t)m * C_;
        float a = 0.f;
#pragma unroll
        for (int cq = 0; cq < 16; ++cq) {
            float4 n4 = *reinterpret_cast<const float4*>(xn + cq * 4);
            float4 m4 = *reinterpret_cast<const float4*>(xm + cq * 4);
            a = __fadd_rn(a, __fmul_rn(n4.x, m4.x));
            a = __fadd_rn(a, __fmul_rn(n4.y, m4.y));
            a = __fadd_rn(a, __fmul_rn(n4.z, m4.z));
            a = __fadd_rn(a, __fmul_rn(n4.w, m4.w));
        }
        dl2[row][ci] = __fadd_rn(__fsub_rn(sqf[bN + n0 + row], __fmul_rn(2.0f, a)),
                                 sqf[bN + m]);
    }
    __syncthreads();
#pragma unroll 1
    for (int t2 = 0; t2 < 6; ++t2) {
        int task = tid + t2 * 256;
        int row = task / 24, ci = task - row * 24;
        int m = cl[row][ci];
        float di = dl2[row][ci];
        int rank = 0;
#pragma unroll
        for (int j = 0; j < CAND; ++j) {
            float dj = dl2[row][j];
            int mj = cl[row][j];
            rank += (dj < di || (dj == di && mj < m)) ? 1 : 0;
        }
        if (rank < K_)
            idxf[((size_t)bN + n0 + row) * K_ + rank] = (float)m;
    }
}

// K2b fallback (only when xrT is unavailable): exact rescore from strided x.
__global__ __launch_bounds__(256) void k_rescore(const float* __restrict__ x,
                                                 const float* __restrict__ sqf,
                                                 const unsigned short* __restrict__ candu,
                                                 float* __restrict__ idxf) {
    int tid = threadIdx.x;
    int w = tid >> 6, lane = tid & 63;
    size_t grow = (size_t)blockIdx.x * 4 + w;
    int b = (int)(grow >> 11), n = (int)(grow & (N_ - 1));
    const float* xb = x + (size_t)b * C_ * N_;
    float d = 0.f;
    unsigned m = 0xFFFFFFFFu;
    if (lane < CAND) {
        m = candu[grow * CAND + lane];
        float a = 0.f;
#pragma unroll 8
        for (int c = 0; c < C_; ++c)
            a = __fadd_rn(a, __fmul_rn(xb[(size_t)c * N_ + n], xb[(size_t)c * N_ + m]));
        d = __fadd_rn(__fsub_rn(sqf[b * N_ + n], __fmul_rn(2.0f, a)), sqf[b * N_ + m]);
    }
    int rank = 0;
#pragma unroll 1
    for (int j = 0; j < CAND; ++j) {
        float dj = __shfl(d, j, 64);
        unsigned mj = (unsigned)__shfl((int)m, j, 64);
        if (lane < CAND && (dj < d || (dj == d && mj < m))) ++rank;
    }
    if (lane < CAND && rank < K_)
        idxf[grow * K_ + rank] = (float)m;
}

// K4: out[b][o][n] = leaky( s[o]*(u + max_k Yt[b][idx[n][k]][o]) + t[o] )
// float4 restructure: wave-uniform o-quad -> 1 broadcast b128 + 1 b32 per c
// for 4 outputs (4x fewer LDS reads than scalar); idx row hoisted once.
__global__ __launch_bounds__(256) void k_out(const float* __restrict__ x,
                                             const float* __restrict__ W,
                                             const float* __restrict__ gamma,
                                             const float* __restrict__ beta,
                                             const float* __restrict__ rmean,
                                             const float* __restrict__ rvar,
                                             const float* __restrict__ Yt,
                                             const float* __restrict__ idxf,
                                             float* __restrict__ out) {
    __shared__ float Bl[C_ * 64];
    __shared__ float xl[C_ * 64];
    __shared__ float resl[64 * 65];
    __shared__ float sl[64], tl[64];
    int tid = threadIdx.x;
    int bid = blockIdx.x;
    int b = bid >> 5;
    int n0 = (bid & 31) * 64;
    {
        int o = tid & 63, cb = tid >> 6;
#pragma unroll
        for (int j = 0; j < 16; ++j) {
            int c = cb * 16 + j;
            Bl[c * 64 + o] = W[o * 128 + 64 + c];
            xl[c * 64 + o] = x[((size_t)b * C_ + c) * N_ + n0 + o];
        }
        if (tid < 64) {
            float s = gamma[tid] / sqrtf(rvar[tid] + 1e-5f);
            sl[tid] = s;
            tl[tid] = beta[tid] - rmean[tid] * s;
        }
    }
    __syncthreads();
    int nl = tid & 63, wv2 = tid >> 6;
    const float* ip = idxf + ((size_t)b * N_ + n0 + nl) * K_;
    int mi[K_];
#pragma unroll
    for (int k = 0; k < K_; ++k) mi[k] = (int)ip[k];
    const float* Ytb = Yt + (size_t)b * N_ * C_;
#pragma unroll
    for (int t = 0; t < 4; ++t) {
        int oq = wv2 * 4 + t;              // wave-uniform
        float ax = 0.f, ay = 0.f, az = 0.f, aw = 0.f;
#pragma unroll 8
        for (int c = 0; c < C_; ++c) {
            float xv = xl[c * 64 + nl];
            float4 bl4 = *reinterpret_cast<const float4*>(&Bl[c * 64 + oq * 4]);
            ax = fmaf(bl4.x, xv, ax);
            ay = fmaf(bl4.y, xv, ay);
            az = fmaf(bl4.z, xv, az);
            aw = fmaf(bl4.w, xv, aw);
        }
        float vx = -3.4e38f, vy = -3.4e38f, vz = -3.4e38f, vw = -3.4e38f;
#pragma unroll
        for (int k = 0; k < K_; ++k) {
            float4 y4 = *reinterpret_cast<const float4*>(&Ytb[(size_t)mi[k] * C_ + oq * 4]);
            vx = fmaxf(vx, y4.x);
            vy = fmaxf(vy, y4.y);
            vz = fmaxf(vz, y4.z);
            vw = fmaxf(vw, y4.w);
        }
        float h0 = ax + vx, h1 = ay + vy, h2 = az + vz, h3 = aw + vw;
        int o0 = oq * 4;
        float v0 = sl[o0 + 0] * h0 + tl[o0 + 0];
        float v1 = sl[o0 + 1] * h1 + tl[o0 + 1];
        float v2 = sl[o0 + 2] * h2 + tl[o0 + 2];
        float v3 = sl[o0 + 3] * h3 + tl[o0 + 3];
        v0 = v0 > 0.f ? v0 : 0.2f * v0;
        v1 = v1 > 0.f ? v1 : 0.2f * v1;
        v2 = v2 > 0.f ? v2 : 0.2f * v2;
        v3 = v3 > 0.f ? v3 : 0.2f * v3;
        resl[(o0 + 0) * 65 + nl] = v0;
        resl[(o0 + 1) * 65 + nl] = v1;
        resl[(o0 + 2) * 65 + nl] = v2;
        resl[(o0 + 3) * 65 + nl] = v3;
    }
    __syncthreads();
    {
        int nl2 = tid & 63, ob = tid >> 6;
#pragma unroll
        for (int j = 0; j < 16; ++j) {
            int o2 = ob * 16 + j;
            out[((size_t)b * C_ + o2) * N_ + n0 + nl2] = resl[o2 * 65 + nl2];
        }
    }
}

extern "C" void kernel_launch(void* const* d_in, const int* in_sizes, int n_in,
                              void* d_out, int out_size, void* d_ws, size_t ws_size,
                              hipStream_t stream) {
    const float* x     = (const float*)d_in[0];
    const float* W     = (const float*)d_in[1];
    const float* gamma = (const float*)d_in[2];
    const float* beta  = (const float*)d_in[3];
    const float* rmean = (const float*)d_in[4];
    const float* rvar  = (const float*)d_in[5];

    float* out  = (float*)d_out;                         // [16][64][2048]
    float* idxf = out + (size_t)B_ * C_ * N_;            // [16][2048][20] as floats

    char* ws = (char*)d_ws;
    // layout: sqf 128K | candu u16x24 1.5M | xh 4M | xrT 8M | [Yt 8M if room]
    float* sqf            = (float*)ws;
    unsigned short* candu = (unsigned short*)(ws + 131072);
    unsigned short* xh    = (unsigned short*)(ws + 131072 + 1572864);
    size_t off_xrT        = 131072 + 1572864 + 4194304;              // 5.90 MB
    size_t need_xrT       = off_xrT + 8388608;                       // 14.28 MB (< r9-proven 15.86)
    size_t need_fused     = need_xrT + 8388608;                      // 22.68 MB
    float* xrT            = (ws_size >= need_xrT) ? (float*)(ws + off_xrT) : nullptr;
    bool fused            = (ws_size >= need_fused);
    float* Yt             = fused ? (float*)(ws + need_xrT) : (float*)(ws + 131072);

    k_sq     <<<B_ * N_ / 128, 128, 0, stream>>>(x, sqf, xh, xrT, fused ? Yt : nullptr, W);
    k_dist   <<<B_ * 32, 256, 0, stream>>>(xh, sqf, xrT, idxf, candu);
    if (!xrT)
        k_rescore<<<B_ * N_ / 4, 256, 0, stream>>>(x, sqf, candu, idxf);
    if (!fused)
        k_y  <<<B_ * (N_ / 64), 256, 0, stream>>>(x, W, Yt);
    k_out    <<<B_ * (N_ / 64), 256, 0, stream>>>(x, W, gamma, beta, rmean, rvar, Yt, idxf, out);
}